// Round 4
// baseline (197.652 us; speedup 1.0000x reference)
//
#include <hip/hip_runtime.h>

// B=4096, D=64, DM=256, K=32, KA=16, S=50
#define SQUARINGS 8

// ---- workspace layout (float offsets); 418 KB total ----
#define OFF_XQ   0        // [65][256]  Zf@Wq   (k1a out, k1b in)
#define OFF_M    16640    // [256][64]  Wo@fW   (k1a out, k1b in)
#define OFF_G    33024    // [64][64]   fW^T fW (k1a out, k2-sigma in)
#define OFF_T1   37120    // [65][256]  Zf@Wq@Wk^T (k1b out, k1c in)
#define OFF_WVM  53760    // [256][64]  Wv@M    (k1b out, k1c in)
#define OFF_PLm  70144    // [65][64]   PL[:,0:64] (rows 0..64, row 64 = zb side)
#define OFF_PLc  74304    // [72]       PL[:,64]   (lat-bias column, rows 0..64)
#define OFF_PCm  74376    // [65][64]
#define OFF_PCc  78536    // [72]
#define OFF_CK2  78608    // [65][48]   chart q-dots folded to z-space
#define OFF_ANCT 81728    // [64][48]   anchors transposed
#define OFF_ANCN 84800    // [64]       |anchor_s|^2 (48 used, rest 0)
#define OFF_VM   84864    // [48][64]   emb@Wv@M
#define OFF_LM   87936    // [65][64]   Lf@Wv@M
#define OFF_CM   92096    // [65][64]   Cf@Wv@M
#define OFF_RS   96256    // 1/sigma
#define OFF_A    96320    // [4096] sigma-scaled part
#define OFF_Bc   100416   // [4096] sigma-free part   (end 104512 floats = 418 KB)

__device__ __forceinline__ float wred(float v) {
  #pragma unroll
  for (int m = 32; m >= 1; m >>= 1) v += __shfl_xor(v, m, 64);
  return v;
}

// ===================== K1a: XQ = Zf@Wq, M = Wo@fW, G = fW^T fW  (580 blocks) =====================
__global__ __launch_bounds__(256)
void k1a(const float* __restrict__ zW, const float* __restrict__ zb,
         const float* __restrict__ Wq, const float* __restrict__ Wo,
         const float* __restrict__ fW, float* __restrict__ ws) {
  __shared__ float red[256];
  const int t = threadIdx.x, b = blockIdx.x;
  const float* Arow; const float* Bm;
  int astride = 1, bstride, jbase = 0, dstBase;
  if (b < 260) {                 // XQ: r<65 rows (row 64 = zb), 4 col-chunks
    int r = b >> 2; jbase = (b & 3) * 64;
    Arow = (r < 64) ? zW + r * 256 : zb;
    Bm = Wq; bstride = 256;
    dstBase = OFF_XQ + r * 256 + jbase;
  } else if (b < 516) {          // M = Wo @ fW
    int i = b - 260;
    Arow = Wo + i * 256; Bm = fW; bstride = 64;
    dstBase = OFF_M + i * 64;
  } else {                       // G = fW^T fW
    int i = b - 516;
    Arow = fW + i; astride = 64; Bm = fW; bstride = 64;
    dstBase = OFF_G + i * 64;
  }
  const int j = t & 63, ks = t >> 6;
  const float* ap = Arow + (ks * 64) * astride;
  const float* bp = Bm + (ks * 64) * bstride + jbase + j;
  float a0 = 0.f, a1 = 0.f, a2 = 0.f, a3 = 0.f;
  #pragma unroll 4
  for (int k = 0; k < 64; k += 4) {
    a0 += ap[(k + 0) * astride] * bp[(k + 0) * bstride];
    a1 += ap[(k + 1) * astride] * bp[(k + 1) * bstride];
    a2 += ap[(k + 2) * astride] * bp[(k + 2) * bstride];
    a3 += ap[(k + 3) * astride] * bp[(k + 3) * bstride];
  }
  red[t] = (a0 + a1) + (a2 + a3);
  __syncthreads();
  if (t < 64) ws[dstBase + t] = red[t] + red[64 + t] + red[128 + t] + red[192 + t];
}

// ===================== K1b: T1 = XQ@Wk^T, WVM = Wv@M  (516 blocks) =====================
__global__ __launch_bounds__(256)
void k1b(const float* __restrict__ Wk, const float* __restrict__ Wv,
         float* __restrict__ ws) {
  __shared__ float red[256];
  const int t = threadIdx.x, b = blockIdx.x;
  const int j = t & 63, ks = t >> 6;
  float a0 = 0.f, a1 = 0.f, a2 = 0.f, a3 = 0.f;
  if (b < 260) {                 // T1[r][e] = sum_j XQ[r][j] * Wk[e][j]
    int r = b >> 2, jbase = (b & 3) * 64;
    const float* ap = ws + OFF_XQ + r * 256 + ks * 64;
    const float* bp = Wk + (jbase + j) * 256 + ks * 64;
    #pragma unroll 4
    for (int k = 0; k < 64; k += 4) {
      a0 += ap[k] * bp[k];     a1 += ap[k + 1] * bp[k + 1];
      a2 += ap[k + 2] * bp[k + 2]; a3 += ap[k + 3] * bp[k + 3];
    }
    red[t] = (a0 + a1) + (a2 + a3);
    __syncthreads();
    if (t < 64) ws[OFF_T1 + r * 256 + jbase + t] = red[t] + red[64 + t] + red[128 + t] + red[192 + t];
  } else {                       // WVM[c][d] = sum_e Wv[c][e] * M[e][d]
    int c = b - 260;
    const float* ap = Wv + c * 256 + ks * 64;
    const float* bp = ws + OFF_M + (ks * 64) * 64 + j;
    #pragma unroll 4
    for (int k = 0; k < 64; k += 4) {
      a0 += ap[k] * bp[(k + 0) * 64];     a1 += ap[k + 1] * bp[(k + 1) * 64];
      a2 += ap[k + 2] * bp[(k + 2) * 64]; a3 += ap[k + 3] * bp[(k + 3) * 64];
    }
    red[t] = (a0 + a1) + (a2 + a3);
    __syncthreads();
    if (t < 64) ws[OFF_WVM + c * 64 + t] = red[t] + red[64 + t] + red[128 + t] + red[192 + t];
  }
}

// ===================== K1c: PL/PC/CK2/VM/LM/CM + anchors  (375 blocks) =====================
__global__ __launch_bounds__(256)
void k1c(const float* __restrict__ latW, const float* __restrict__ latb,
         const float* __restrict__ codeW, const float* __restrict__ codeb,
         const float* __restrict__ chemb, const float* __restrict__ aemb,
         const float* __restrict__ aanc, const float* __restrict__ chanc,
         float* __restrict__ ws) {
  __shared__ float red[256];
  const int t = threadIdx.x, b = blockIdx.x;
  const int j = t & 63, ks = t >> 6;

  if (b == 374) {                // ANCT [64 d][48 s] + ANCN
    for (int e = t; e < 3072; e += 256) {
      int d = e / 48, s = e - d * 48;
      const float* a = (s < 16) ? (aanc + s * 64) : (chanc + (s - 16) * 64);
      ws[OFF_ANCT + e] = a[d];
    }
    if (t < 64) {
      float n = 0.f;
      if (t < 48) {
        const float* a = (t < 16) ? (aanc + t * 64) : (chanc + (t - 16) * 64);
        #pragma unroll 4
        for (int d = 0; d < 64; ++d) n += a[d] * a[d];
      }
      ws[OFF_ANCN + t] = n;      // zero for 48..63
    }
    return;
  }
  if (b == 65) {                 // PLc[r] = T1[r]·latb ; PCc[r] = T1[r]·codeb
    if (t < 65) {
      const float* ap = ws + OFF_T1 + t * 256;
      float acc = 0.f;
      #pragma unroll 4
      for (int e = 0; e < 256; ++e) acc += ap[e] * latb[e];
      ws[OFF_PLc + t] = acc;
    } else if (t >= 128 && t < 193) {
      int r = t - 128;
      const float* ap = ws + OFF_T1 + r * 256;
      float acc = 0.f;
      #pragma unroll 4
      for (int e = 0; e < 256; ++e) acc += ap[e] * codeb[e];
      ws[OFF_PCc + r] = acc;
    }
    return;
  }

  float a0 = 0.f, a1 = 0.f, a2 = 0.f, a3 = 0.f;
  if (b < 196) {                 // row-stream: PLm / PCm / CK2
    int r, dstBase, nout = 64;
    const float* brow;
    if (b < 65)       { r = b;       brow = latW + j * 256;  dstBase = OFF_PLm + r * 64; }
    else if (b < 131) { r = b - 66;  brow = codeW + j * 256; dstBase = OFF_PCm + r * 64; }
    else {
      r = b - 131; nout = 48;
      int s = (j < 48) ? j : 47;
      brow = (s < 16) ? (aemb + s * 256) : (chemb + (s - 16) * 256);
      dstBase = OFF_CK2 + r * 48;
    }
    const float* ap = ws + OFF_T1 + r * 256 + ks * 64;
    const float* bp = brow + ks * 64;
    #pragma unroll 4
    for (int k = 0; k < 64; k += 4) {
      a0 += ap[k] * bp[k];         a1 += ap[k + 1] * bp[k + 1];
      a2 += ap[k + 2] * bp[k + 2]; a3 += ap[k + 3] * bp[k + 3];
    }
    red[t] = (a0 + a1) + (a2 + a3);
    __syncthreads();
    if (t < nout) ws[dstBase + t] = red[t] + red[64 + t] + red[128 + t] + red[192 + t];
  } else {                       // bstride=64 on WVM: VM / LM / CM
    const float* Arow; int dstBase;
    if (b < 244)      { int s = b - 196; Arow = (s < 16) ? (aemb + s * 256) : (chemb + (s - 16) * 256); dstBase = OFF_VM + s * 64; }
    else if (b < 309) { int r = b - 244; Arow = (r < 64) ? (latW + r * 256) : latb;  dstBase = OFF_LM + r * 64; }
    else              { int r = b - 309; Arow = (r < 64) ? (codeW + r * 256) : codeb; dstBase = OFF_CM + r * 64; }
    const float* ap = Arow + ks * 64;
    const float* bp = ws + OFF_WVM + (ks * 64) * 64 + j;
    #pragma unroll 4
    for (int k = 0; k < 64; k += 4) {
      a0 += ap[k] * bp[(k + 0) * 64];     a1 += ap[k + 1] * bp[(k + 1) * 64];
      a2 += ap[k + 2] * bp[(k + 2) * 64]; a3 += ap[k + 3] * bp[(k + 3) * 64];
    }
    red[t] = (a0 + a1) + (a2 + a3);
    __syncthreads();
    if (t < 64) ws[dstBase + t] = red[t] + red[64 + t] + red[128 + t] + red[192 + t];
  }
}

// ===================== K2: wave-per-2-batches, zero barriers in main path =====================
__global__ __launch_bounds__(256)
void k2_main(const float* __restrict__ z, const float* __restrict__ rw,
             const float* __restrict__ az, const float* __restrict__ arw,
             const float* __restrict__ acz, const float* __restrict__ ctrl,
             const float* __restrict__ ecov, const float* __restrict__ fb,
             float* __restrict__ ws) {
  __shared__ __align__(16) float sm[8772];     // sigma block only
  const int t = threadIdx.x;
  const int wv = t >> 6, ln = t & 63;

  if (blockIdx.x == 512) {
    // ---------- sigma: 8 trace-normalized squarings of G, Rayleigh on global G ----------
    float* HA = sm;
    float* HB = sm + 4352;
    {
      float tv = (t < 64) ? ws[OFF_G + t * 65] : 0.f;
      tv = wred(tv);
      if (t == 0) sm[8704] = (tv > 0.f) ? 1.f / tv : 0.f;
    }
    __syncthreads();
    {
      float inv0 = sm[8704];
      for (int e = t; e < 4096; e += 256) {
        int i = e >> 6, jj = e & 63;
        HA[i * 68 + jj] = ws[OFF_G + e] * inv0;
      }
    }
    __syncthreads();
    for (int it = 0; it < SQUARINGS; ++it) {
      float* src = (it & 1) ? HB : HA;
      float* dst = (it & 1) ? HA : HB;
      float acc16[16];
      #pragma unroll
      for (int r = 0; r < 16; ++r) acc16[r] = 0.f;
      for (int half = 0; half < 2; ++half) {
        float cb[32];
        #pragma unroll
        for (int k = 0; k < 32; ++k) cb[k] = src[(half * 32 + k) * 68 + ln];
        #pragma unroll
        for (int r = 0; r < 16; ++r) {
          int i = r * 4 + wv;
          float a = 0.f;
          #pragma unroll
          for (int k4 = 0; k4 < 8; ++k4) {
            float4 a4 = *(const float4*)&src[i * 68 + half * 32 + k4 * 4];
            a += a4.x * cb[k4 * 4] + a4.y * cb[k4 * 4 + 1] + a4.z * cb[k4 * 4 + 2] + a4.w * cb[k4 * 4 + 3];
          }
          acc16[r] += a;
        }
      }
      #pragma unroll
      for (int r = 0; r < 16; ++r) dst[(r * 4 + wv) * 68 + ln] = acc16[r];
      __syncthreads();
      {
        float tv = (t < 64) ? dst[t * 68 + t] : 0.f;
        tv = wred(tv);
        if (t == 0) sm[8704] = (tv > 0.f) ? 1.f / tv : 0.f;
      }
      __syncthreads();
      {
        float sc = sm[8704];
        #pragma unroll
        for (int r = 0; r < 16; ++r) dst[(r * 4 + wv) * 68 + ln] *= sc;
      }
      __syncthreads();
    }
    float* H = (SQUARINGS & 1) ? HB : HA;
    if (t < 64) {
      float cn = 0.f;
      for (int i = 0; i < 64; ++i) { float h = H[i * 68 + t]; cn += h * h; }
      float bv = cn; int bj = t;
      #pragma unroll
      for (int m = 32; m >= 1; m >>= 1) {
        float ov = __shfl_xor(bv, m, 64);
        int   oj = __shfl_xor(bj, m, 64);
        if (ov > bv || (ov == bv && oj < bj)) { bv = ov; bj = oj; }
      }
      if (t == 0) sm[8705] = (float)bj;
    }
    __syncthreads();
    {
      int jmax = (int)sm[8705];
      if (t < 64) sm[8708 + t] = H[t * 68 + jmax];
    }
    __syncthreads();
    if (t < 64) {
      float vi = sm[8708 + t];
      float y = 0.f;
      #pragma unroll 4
      for (int k = 0; k < 64; ++k) y += ws[OFF_G + t * 64 + k] * sm[8708 + k];
      float num = wred(vi * y);
      float den = wred(vi * vi);
      if (t == 0) {
        float lam = (den > 1e-37f) ? num / den : 0.f;
        lam = fmaxf(lam, 0.f);
        float sg = sqrtf(lam);
        ws[OFF_RS] = 1.f / fmaxf(sg, 1e-8f);
      }
    }
    return;
  }

  // ---------- main: wave wv owns batches bb, bb+1 end-to-end; NO barriers ----------
  const int bb = blockIdx.x * 8 + wv * 2;
  float z0 = z[bb * 64 + ln],        z1 = z[(bb + 1) * 64 + ln];
  float a0 = az[bb * 64 + ln],       a1 = az[(bb + 1) * 64 + ln];
  float c0 = acz[bb * 64 + ln],      c1 = acz[(bb + 1) * 64 + ln];

  // distances + |z|^2 (6 wave reductions; all lanes end with sums)
  float dL0 = wred((z0 - a0) * (z0 - a0));
  float dL1 = wred((z1 - a1) * (z1 - a1));
  float dC0 = wred((z0 - c0) * (z0 - c0));
  float dC1 = wred((z1 - c1) * (z1 - c1));
  float zn0 = wred(z0 * z0);
  float zn1 = wred(z1 * z1);

  // lat/code bilinear scores: [z,1] PL [az,1]^T
  const float* plm = ws + OFF_PLm + ln;
  const float* pcm = ws + OFF_PCm + ln;
  float uL0 = plm[64 * 64], uL1 = uL0;     // bias row PL[64][d]
  float uC0 = pcm[64 * 64], uC1 = uC0;
  #pragma unroll 8
  for (int k = 0; k < 64; ++k) {
    float pm = plm[k * 64], pc = pcm[k * 64];
    float zk0 = __shfl(z0, k, 64), zk1 = __shfl(z1, k, 64);
    uL0 = fmaf(zk0, pm, uL0); uL1 = fmaf(zk1, pm, uL1);
    uC0 = fmaf(zk0, pc, uC0); uC1 = fmaf(zk1, pc, uC1);
  }
  float plc = ws[OFF_PLc + ln], pcc = ws[OFF_PCc + ln];
  float plcc = ws[OFF_PLc + 64], pccc = ws[OFF_PCc + 64];
  float sL0 = wred(uL0 * a0 + z0 * plc) + plcc;
  float sL1 = wred(uL1 * a1 + z1 * plc) + plcc;
  float sC0 = wred(uC0 * c0 + z0 * pcc) + pccc;
  float sC1 = wred(uC1 * c1 + z1 * pcc) + pccc;
  float scl0 = sL0 * 0.0625f - dL0, scl1 = sL1 * 0.0625f - dL1;
  float scc0 = sC0 * 0.0625f - dC0, scc1 = sC1 * 0.0625f - dC1;

  // chart scores: lane ln = chart s (<48)
  const float* ck = ws + OFF_CK2 + ln;     // [k][48]
  const float* an = ws + OFF_ANCT + ln;    // [d][48]
  float ca0 = ck[64 * 48], ca1 = ca0;      // bias row CK2[64][s]
  float za0 = 0.f, za1 = 0.f;
  #pragma unroll 8
  for (int k = 0; k < 64; ++k) {
    float cv = ck[k * 48], av = an[k * 48];
    float zk0 = __shfl(z0, k, 64), zk1 = __shfl(z1, k, 64);
    ca0 = fmaf(zk0, cv, ca0); ca1 = fmaf(zk1, cv, ca1);
    za0 = fmaf(zk0, av, za0); za1 = fmaf(zk1, av, za1);
  }
  float ancn = ws[OFF_ANCN + ln];
  float fold0 = 1.f, fold1 = 1.f;
  if (ln < 16)      { fold0 = arw[bb * 16 + ln];        fold1 = arw[(bb + 1) * 16 + ln]; }
  else if (ln < 48) { fold0 = rw[bb * 32 + (ln - 16)];  fold1 = rw[(bb + 1) * 32 + (ln - 16)]; }
  float sc0 = fold0 * ca0 * 0.0625f - (zn0 - 2.f * za0 + ancn);
  float sc1 = fold1 * ca1 * 0.0625f - (zn1 - 2.f * za1 + ancn);
  if (ln == 48) { sc0 = scl0; sc1 = scl1; }
  if (ln == 49) { sc0 = scc0; sc1 = scc1; }
  if (ln > 49)  { sc0 = -1e30f; sc1 = -1e30f; }

  // softmax over 50 (wave-parallel) + fold routing weights into w
  float mx0 = sc0, mx1 = sc1;
  #pragma unroll
  for (int m = 32; m >= 1; m >>= 1) {
    mx0 = fmaxf(mx0, __shfl_xor(mx0, m, 64));
    mx1 = fmaxf(mx1, __shfl_xor(mx1, m, 64));
  }
  float ev0 = (ln < 50) ? __expf(sc0 - mx0) : 0.f;
  float ev1 = (ln < 50) ? __expf(sc1 - mx1) : 0.f;
  float sum0 = wred(ev0), sum1 = wred(ev1);
  float w0 = ev0 * (1.f / sum0) * fold0;   // fold=1 for lanes 48/49
  float w1 = ev1 * (1.f / sum1) * fold1;

  // g[d] = sum_{s<48} w_s VM[s][d] + w48*([az,1]@LM)[d] + w49*([acz,1]@CM)[d]
  float g0 = 0.f, g1 = 0.f;
  const float* vm = ws + OFF_VM + ln;
  #pragma unroll 8
  for (int s = 0; s < 48; ++s) {
    float v = vm[s * 64];
    float s0 = __shfl(w0, s, 64), s1 = __shfl(w1, s, 64);
    g0 = fmaf(s0, v, g0); g1 = fmaf(s1, v, g1);
  }
  const float* lm = ws + OFF_LM + ln;
  const float* cm = ws + OFF_CM + ln;
  float l0 = lm[64 * 64], l1 = l0;         // bias rows
  float m0 = cm[64 * 64], m1 = m0;
  #pragma unroll 8
  for (int k = 0; k < 64; ++k) {
    float lv = lm[k * 64], cv = cm[k * 64];
    float ak0 = __shfl(a0, k, 64), ak1 = __shfl(a1, k, 64);
    float qk0 = __shfl(c0, k, 64), qk1 = __shfl(c1, k, 64);
    l0 = fmaf(ak0, lv, l0); l1 = fmaf(ak1, lv, l1);
    m0 = fmaf(qk0, cv, m0); m1 = fmaf(qk1, cv, m1);
  }
  float w48_0 = __shfl(w0, 48, 64), w49_0 = __shfl(w0, 49, 64);
  float w48_1 = __shfl(w1, 48, 64), w49_1 = __shfl(w1, 49, 64);
  g0 += w48_0 * l0 + w49_0 * m0;
  g1 += w48_1 * l1 + w49_1 * m1;

  // epilogue: projections off exact covector -> A (sigma-scaled), B (sigma-free)
  float fbv = fb[ln];
  #pragma unroll
  for (int s = 0; s < 2; ++s) {
    float g  = (s == 0) ? g0 : g1;
    int bbs  = bb + s;
    float cc = ctrl[bbs * 64 + ln];
    float ee = ecov[bbs * 64 + ln];
    float gc = wred(g * cc);
    float ge = wred(g * ee);
    float ec = wred(ee * cc);
    float en = wred(ee * ee);
    float fc = wred(fbv * cc);
    float fe = wred(fbv * ee);
    if (ln == 0) {
      float A, Bv;
      if (en > 1e-8f) { float r = ec / en; A = gc - ge * r; Bv = fc - fe * r; }
      else { A = gc; Bv = fc; }
      ws[OFF_A  + bbs] = A;
      ws[OFF_Bc + bbs] = Bv;
    }
  }
}

// ===================== K3: apply 1/sigma =====================
__global__ __launch_bounds__(256)
void k3_out(const float* __restrict__ ws, float* __restrict__ out) {
  int b = blockIdx.x * 256 + threadIdx.x;
  float rs = ws[OFF_RS];
  out[b] = ws[OFF_A + b] * rs + ws[OFF_Bc + b];
}

extern "C" void kernel_launch(void* const* d_in, const int* in_sizes, int n_in,
                              void* d_out, int out_size, void* d_ws, size_t ws_size,
                              hipStream_t stream) {
  const float* z     = (const float*)d_in[0];
  const float* rw    = (const float*)d_in[1];
  const float* az    = (const float*)d_in[2];
  const float* arw   = (const float*)d_in[3];
  const float* acz   = (const float*)d_in[4];
  const float* ctrl  = (const float*)d_in[5];
  const float* ecov  = (const float*)d_in[6];
  const float* chemb = (const float*)d_in[7];
  const float* chanc = (const float*)d_in[8];
  const float* aemb  = (const float*)d_in[9];
  const float* aanc  = (const float*)d_in[10];
  const float* zW    = (const float*)d_in[11];
  const float* zb    = (const float*)d_in[12];
  const float* latW  = (const float*)d_in[13];
  const float* latb  = (const float*)d_in[14];
  const float* codeW = (const float*)d_in[15];
  const float* codeb = (const float*)d_in[16];
  const float* Wq    = (const float*)d_in[17];
  const float* Wk    = (const float*)d_in[18];
  const float* Wv    = (const float*)d_in[19];
  const float* Wo    = (const float*)d_in[20];
  const float* fW    = (const float*)d_in[21];
  const float* fb    = (const float*)d_in[22];
  float* ws  = (float*)d_ws;
  float* out = (float*)d_out;

  k1a<<<580, 256, 0, stream>>>(zW, zb, Wq, Wo, fW, ws);
  k1b<<<516, 256, 0, stream>>>(Wk, Wv, ws);
  k1c<<<375, 256, 0, stream>>>(latW, latb, codeW, codeb, chemb, aemb, aanc, chanc, ws);
  k2_main<<<513, 256, 0, stream>>>(z, rw, az, arw, acz, ctrl, ecov, fb, ws);
  k3_out<<<16, 256, 0, stream>>>(ws, out);
}

// Round 5
// 192.826 us; speedup vs baseline: 1.0250x; 1.0250x over previous
//
#include <hip/hip_runtime.h>

// B=4096, D=64, DM=256, K=32, KA=16, S=50
#define SQUARINGS 5
#define PITERS 20

// ---- workspace layout (float offsets); peak 617 KB ----
// stage-1 (dead after k1b; A/Bc/RS overlay this region):
#define OFF_XQ   0        // [65][256]  Zf@Wq
#define OFF_KL   16640    // [65][256]  Lf@Wk
#define OFF_KC   33280    // [65][256]  Cf@Wk
#define OFF_VL   49920    // [65][256]  Lf@Wv
#define OFF_VC   66560    // [65][256]  Cf@Wv
#define OFF_KE   83200    // [48][256]  EMB@Wk
#define OFF_VE   95488    // [48][256]  EMB@Wv
#define OFF_M    107776   // [256][64]  Wo@fW
#define OFF_G    124160   // [64][64]   fW^T fW
// stage-2 (k2 inputs):
#define OFF_PLm  128256   // [65][64]
#define OFF_PLc  132416   // [72]
#define OFF_PCm  132488   // [65][64]
#define OFF_PCc  136648   // [72]
#define OFF_CK2  136720   // [65][48]
#define OFF_ANCT 139840   // [64][48]
#define OFF_ANCN 142912   // [64]
#define OFF_VM   142976   // [48][64]
#define OFF_LM   146048   // [65][64]
#define OFF_CM   150208   // [65][64]  (end 154368)
// overlay into dead stage-1 region:
#define OFF_RS   0        // 1/sigma
#define OFF_A    64       // [4096]
#define OFF_Bc   4224     // [4096]

__device__ __forceinline__ float wred(float v) {
  #pragma unroll
  for (int m = 32; m >= 1; m >>= 1) v += __shfl_xor(v, m, 64);
  return v;
}

// ===================== K1a: all input-only folds, 2004 light blocks =====================
__global__ __launch_bounds__(256)
void k1a(const float* __restrict__ chemb, const float* __restrict__ aemb,
         const float* __restrict__ zW, const float* __restrict__ zb,
         const float* __restrict__ latW, const float* __restrict__ latb,
         const float* __restrict__ codeW, const float* __restrict__ codeb,
         const float* __restrict__ Wq, const float* __restrict__ Wk,
         const float* __restrict__ Wv, const float* __restrict__ Wo,
         const float* __restrict__ fW, float* __restrict__ ws) {
  __shared__ float red[256];
  const int t = threadIdx.x, b = blockIdx.x;
  const float* Arow; const float* Bm;
  int astride = 1, bstride = 256, jbase = 0, dstBase;

  if (b < 1300) {                 // XQ/KL/KC/VL/VC: 5 x 65 rows x 4 col-chunks
    int u = b / 260, r2 = b - u * 260;
    int row = r2 >> 2; jbase = (r2 & 3) * 64;
    const float* Wmat; const float* bias;
    if (u == 0)      { Wmat = zW;    bias = zb;    Bm = Wq; }
    else if (u == 1) { Wmat = latW;  bias = latb;  Bm = Wk; }
    else if (u == 2) { Wmat = codeW; bias = codeb; Bm = Wk; }
    else if (u == 3) { Wmat = latW;  bias = latb;  Bm = Wv; }
    else             { Wmat = codeW; bias = codeb; Bm = Wv; }
    Arow = (row < 64) ? (Wmat + row * 256) : bias;
    dstBase = u * 16640 + row * 256 + jbase;        // OFF_XQ == 0
  } else if (b < 1684) {          // KE/VE: 2 x 48 rows x 4 col-chunks
    int rr = b - 1300;
    int isV = rr >= 192; int rr2 = isV ? rr - 192 : rr;
    int s = rr2 >> 2; jbase = (rr2 & 3) * 64;
    Bm = isV ? Wv : Wk;
    Arow = (s < 16) ? (aemb + s * 256) : (chemb + (s - 16) * 256);
    dstBase = (isV ? OFF_VE : OFF_KE) + s * 256 + jbase;
  } else if (b < 1940) {          // M = Wo @ fW
    int i = b - 1684;
    Arow = Wo + i * 256; Bm = fW; bstride = 64;
    dstBase = OFF_M + i * 64;
  } else {                        // G = fW^T fW
    int i = b - 1940;
    Arow = fW + i; astride = 64; Bm = fW; bstride = 64;
    dstBase = OFF_G + i * 64;
  }

  const int j = t & 63, ks = t >> 6;
  const float* ap = Arow + (ks * 64) * astride;
  const float* bp = Bm + (ks * 64) * bstride + jbase + j;
  float a0 = 0.f, a1 = 0.f, a2 = 0.f, a3 = 0.f;
  #pragma unroll 4
  for (int k = 0; k < 64; k += 4) {
    a0 += ap[(k + 0) * astride] * bp[(k + 0) * bstride];
    a1 += ap[(k + 1) * astride] * bp[(k + 1) * bstride];
    a2 += ap[(k + 2) * astride] * bp[(k + 2) * bstride];
    a3 += ap[(k + 3) * astride] * bp[(k + 3) * bstride];
  }
  red[t] = (a0 + a1) + (a2 + a3);
  __syncthreads();
  if (t < 64) ws[dstBase + t] = red[t] + red[64 + t] + red[128 + t] + red[192 + t];
}

// ===================== K1b: pairwise folds, 375 blocks =====================
__global__ __launch_bounds__(256)
void k1b(const float* __restrict__ latb, const float* __restrict__ codeb,
         const float* __restrict__ aanc, const float* __restrict__ chanc,
         float* __restrict__ ws) {
  __shared__ float red[256];
  const int t = threadIdx.x, b = blockIdx.x;

  if (b == 374) {                 // ANCT [64 d][48 s] + ANCN
    for (int e = t; e < 3072; e += 256) {
      int d = e / 48, s = e - d * 48;
      const float* a = (s < 16) ? (aanc + s * 64) : (chanc + (s - 16) * 64);
      ws[OFF_ANCT + e] = a[d];
    }
    if (t < 64) {
      float n = 0.f;
      if (t < 48) {
        const float* a = (t < 16) ? (aanc + t * 64) : (chanc + (t - 16) * 64);
        #pragma unroll 4
        for (int d = 0; d < 64; ++d) n += a[d] * a[d];
      }
      ws[OFF_ANCN + t] = n;
    }
    return;
  }
  if (b == 373) {                 // PLc[r] = XQ[r]·KL[64] ; PCc[r] = XQ[r]·KC[64]
    if (t < 65) {
      const float* ap = ws + OFF_XQ + t * 256;
      const float* bp = ws + OFF_KL + 64 * 256;
      float acc = 0.f;
      #pragma unroll 4
      for (int e = 0; e < 256; ++e) acc += ap[e] * bp[e];
      ws[OFF_PLc + t] = acc;
    } else if (t >= 128 && t < 193) {
      int r = t - 128;
      const float* ap = ws + OFF_XQ + r * 256;
      const float* bp = ws + OFF_KC + 64 * 256;
      float acc = 0.f;
      #pragma unroll 4
      for (int e = 0; e < 256; ++e) acc += ap[e] * bp[e];
      ws[OFF_PCc + r] = acc;
    }
    return;
  }

  const int j = t & 63, ks = t >> 6;
  const float* ap; const float* bp;
  int bstride, dstBase, nout = 64;
  if (b < 325) {
    int g = b / 65, r = b - g * 65;
    const float* A = ws + ((g < 3) ? OFF_XQ : (g == 3 ? OFF_VL : OFF_VC)) + r * 256;
    if (g == 0)      { bp = ws + OFF_KL + j * 256 + ks * 64; bstride = 1; dstBase = OFF_PLm + r * 64; }
    else if (g == 1) { bp = ws + OFF_KC + j * 256 + ks * 64; bstride = 1; dstBase = OFF_PCm + r * 64; }
    else if (g == 2) { int jj = (j < 48) ? j : 47;
                       bp = ws + OFF_KE + jj * 256 + ks * 64; bstride = 1; dstBase = OFF_CK2 + r * 48; nout = 48; }
    else if (g == 3) { bp = ws + OFF_M + (ks * 64) * 64 + j; bstride = 64; dstBase = OFF_LM + r * 64; }
    else             { bp = ws + OFF_M + (ks * 64) * 64 + j; bstride = 64; dstBase = OFF_CM + r * 64; }
    ap = A + ks * 64;
  } else {                        // VM[s] = VE[s]@M
    int s = b - 325;
    ap = ws + OFF_VE + s * 256 + ks * 64;
    bp = ws + OFF_M + (ks * 64) * 64 + j; bstride = 64;
    dstBase = OFF_VM + s * 64;
  }
  float a0 = 0.f, a1 = 0.f, a2 = 0.f, a3 = 0.f;
  #pragma unroll 4
  for (int k = 0; k < 64; k += 4) {
    a0 += ap[k + 0] * bp[(k + 0) * bstride];
    a1 += ap[k + 1] * bp[(k + 1) * bstride];
    a2 += ap[k + 2] * bp[(k + 2) * bstride];
    a3 += ap[k + 3] * bp[(k + 3) * bstride];
  }
  red[t] = (a0 + a1) + (a2 + a3);
  __syncthreads();
  if (t < nout) ws[dstBase + t] = red[t] + red[64 + t] + red[128 + t] + red[192 + t];
}

// ===================== K2: wave-per-2-batches main + fast sigma block =====================
__global__ __launch_bounds__(256)
void k2_main(const float* __restrict__ z, const float* __restrict__ rw,
             const float* __restrict__ az, const float* __restrict__ arw,
             const float* __restrict__ acz, const float* __restrict__ ctrl,
             const float* __restrict__ ecov, const float* __restrict__ fb,
             float* __restrict__ ws) {
  __shared__ __align__(16) float sm[8772];     // sigma block only
  const int t = threadIdx.x;
  const int wv = t >> 6, ln = t & 63;

  if (blockIdx.x == 512) {
    // ---------- sigma: 5 trace-normalized squarings (2 barriers each, reg-scaled)
    // ----------        + 20 one-wave register power iters + Rayleigh on original G
    float* H  = sm;            // [64][68]
    float* GS = sm + 4352;     // [64][68] original G
    {
      float tv = (t < 64) ? ws[OFF_G + t * 65] : 0.f;   // diag
      tv = wred(tv);
      if (t == 0) sm[8704] = (tv > 0.f) ? 1.f / tv : 0.f;
    }
    for (int e = t; e < 4096; e += 256) {
      int i = e >> 6, jj = e & 63;
      GS[i * 68 + jj] = ws[OFF_G + e];
    }
    __syncthreads();
    {
      float inv0 = sm[8704];
      for (int e = t; e < 4096; e += 256) {
        int i = e >> 6, jj = e & 63;
        H[i * 68 + jj] = GS[i * 68 + jj] * inv0;   // same-thread elements, no race
      }
    }
    __syncthreads();
    for (int it = 0; it < SQUARINGS; ++it) {
      float acc[16];
      #pragma unroll
      for (int r = 0; r < 16; ++r) acc[r] = 0.f;
      for (int half = 0; half < 2; ++half) {
        float cb[32];
        #pragma unroll
        for (int k = 0; k < 32; ++k) cb[k] = H[(half * 32 + k) * 68 + ln];
        #pragma unroll
        for (int r = 0; r < 16; ++r) {
          int i = r * 4 + wv;
          float a = 0.f;
          #pragma unroll
          for (int k4 = 0; k4 < 8; ++k4) {
            float4 a4 = *(const float4*)&H[i * 68 + half * 32 + k4 * 4];
            a += a4.x * cb[k4 * 4] + a4.y * cb[k4 * 4 + 1] + a4.z * cb[k4 * 4 + 2] + a4.w * cb[k4 * 4 + 3];
          }
          acc[r] += a;
        }
      }
      // diag partials (static index) -> per-wave trace share
      float dv = 0.f;
      #pragma unroll
      for (int r = 0; r < 16; ++r) dv += (ln == r * 4 + wv) ? acc[r] : 0.f;
      dv = wred(dv);
      if (ln == 0) sm[8705 + wv] = dv;
      __syncthreads();     // all H reads done; trace parts visible
      {
        float tr = sm[8705] + sm[8706] + sm[8707] + sm[8708];
        float sc = (tr > 0.f) ? 1.f / tr : 0.f;
        #pragma unroll
        for (int r = 0; r < 16; ++r) H[(r * 4 + wv) * 68 + ln] = acc[r] * sc;
      }
      __syncthreads();
    }
    if (wv == 0) {
      // v0 = max-norm column of H
      float cn = 0.f;
      #pragma unroll 8
      for (int k = 0; k < 64; ++k) { float h = H[k * 68 + ln]; cn += h * h; }
      float bv = cn; int bj = ln;
      #pragma unroll
      for (int m = 32; m >= 1; m >>= 1) {
        float ov = __shfl_xor(bv, m, 64);
        int   oj = __shfl_xor(bj, m, 64);
        if (ov > bv || (ov == bv && oj < bj)) { bv = ov; bj = oj; }
      }
      int jmax = __shfl(bj, 0, 64);
      float v = H[ln * 68 + jmax];
      // H rows into registers
      float h[64];
      #pragma unroll
      for (int k = 0; k < 64; ++k) h[k] = H[ln * 68 + k];
      // power iterations, all in regs
      for (int pi = 0; pi < PITERS; ++pi) {
        float y = 0.f;
        #pragma unroll
        for (int k = 0; k < 64; ++k) y = fmaf(h[k], __shfl(v, k, 64), y);
        float n2 = wred(y * y);
        v = (n2 > 0.f) ? y * rsqrtf(n2) : 0.f;
      }
      // Rayleigh on original G
      float y = 0.f;
      #pragma unroll 8
      for (int k = 0; k < 64; ++k) y = fmaf(GS[ln * 68 + k], __shfl(v, k, 64), y);
      float num = wred(v * y);
      float den = wred(v * v);
      if (ln == 0) {
        float lam = (den > 1e-37f) ? num / den : 0.f;
        lam = fmaxf(lam, 0.f);
        ws[OFF_RS] = 1.f / fmaxf(sqrtf(lam), 1e-8f);
      }
    }
    return;
  }

  // ---------- main: wave wv owns batches bb, bb+1 end-to-end; NO barriers ----------
  const int bb = blockIdx.x * 8 + wv * 2;
  float z0 = z[bb * 64 + ln],        z1 = z[(bb + 1) * 64 + ln];
  float a0 = az[bb * 64 + ln],       a1 = az[(bb + 1) * 64 + ln];
  float c0 = acz[bb * 64 + ln],      c1 = acz[(bb + 1) * 64 + ln];
  // prefetch epilogue operands early (hide latency under compute)
  float cc0 = ctrl[bb * 64 + ln],    cc1 = ctrl[(bb + 1) * 64 + ln];
  float ee0 = ecov[bb * 64 + ln],    ee1 = ecov[(bb + 1) * 64 + ln];
  float fbv = fb[ln];
  float fold0 = 1.f, fold1 = 1.f;
  if (ln < 16)      { fold0 = arw[bb * 16 + ln];        fold1 = arw[(bb + 1) * 16 + ln]; }
  else if (ln < 48) { fold0 = rw[bb * 32 + (ln - 16)];  fold1 = rw[(bb + 1) * 32 + (ln - 16)]; }

  // distances + |z|^2
  float dL0 = wred((z0 - a0) * (z0 - a0));
  float dL1 = wred((z1 - a1) * (z1 - a1));
  float dC0 = wred((z0 - c0) * (z0 - c0));
  float dC1 = wred((z1 - c1) * (z1 - c1));
  float zn0 = wred(z0 * z0);
  float zn1 = wred(z1 * z1);

  // lat/code bilinear scores: [z,1] PL [az,1]^T
  const float* plm = ws + OFF_PLm + ln;
  const float* pcm = ws + OFF_PCm + ln;
  float uL0 = plm[64 * 64], uL1 = uL0;
  float uC0 = pcm[64 * 64], uC1 = uC0;
  #pragma unroll 8
  for (int k = 0; k < 64; ++k) {
    float pm = plm[k * 64], pc = pcm[k * 64];
    float zk0 = __shfl(z0, k, 64), zk1 = __shfl(z1, k, 64);
    uL0 = fmaf(zk0, pm, uL0); uL1 = fmaf(zk1, pm, uL1);
    uC0 = fmaf(zk0, pc, uC0); uC1 = fmaf(zk1, pc, uC1);
  }
  float plc = ws[OFF_PLc + ln], pcc = ws[OFF_PCc + ln];
  float plcc = ws[OFF_PLc + 64], pccc = ws[OFF_PCc + 64];
  float sL0 = wred(uL0 * a0 + z0 * plc) + plcc;
  float sL1 = wred(uL1 * a1 + z1 * plc) + plcc;
  float sC0 = wred(uC0 * c0 + z0 * pcc) + pccc;
  float sC1 = wred(uC1 * c1 + z1 * pcc) + pccc;
  float scl0 = sL0 * 0.0625f - dL0, scl1 = sL1 * 0.0625f - dL1;
  float scc0 = sC0 * 0.0625f - dC0, scc1 = sC1 * 0.0625f - dC1;

  // chart scores: lane ln = chart s (<48)
  const float* ck = ws + OFF_CK2 + ln;
  const float* an = ws + OFF_ANCT + ln;
  float ca0 = ck[64 * 48], ca1 = ca0;
  float za0 = 0.f, za1 = 0.f;
  #pragma unroll 8
  for (int k = 0; k < 64; ++k) {
    float cv = ck[k * 48], av = an[k * 48];
    float zk0 = __shfl(z0, k, 64), zk1 = __shfl(z1, k, 64);
    ca0 = fmaf(zk0, cv, ca0); ca1 = fmaf(zk1, cv, ca1);
    za0 = fmaf(zk0, av, za0); za1 = fmaf(zk1, av, za1);
  }
  float ancn = ws[OFF_ANCN + ln];
  float sc0 = fold0 * ca0 * 0.0625f - (zn0 - 2.f * za0 + ancn);
  float sc1 = fold1 * ca1 * 0.0625f - (zn1 - 2.f * za1 + ancn);
  if (ln == 48) { sc0 = scl0; sc1 = scl1; }
  if (ln == 49) { sc0 = scc0; sc1 = scc1; }
  if (ln > 49)  { sc0 = -1e30f; sc1 = -1e30f; }

  // softmax over 50 + fold routing weights
  float mx0 = sc0, mx1 = sc1;
  #pragma unroll
  for (int m = 32; m >= 1; m >>= 1) {
    mx0 = fmaxf(mx0, __shfl_xor(mx0, m, 64));
    mx1 = fmaxf(mx1, __shfl_xor(mx1, m, 64));
  }
  float ev0 = (ln < 50) ? __expf(sc0 - mx0) : 0.f;
  float ev1 = (ln < 50) ? __expf(sc1 - mx1) : 0.f;
  float sum0 = wred(ev0), sum1 = wred(ev1);
  float w0 = ev0 * (1.f / sum0) * fold0;
  float w1 = ev1 * (1.f / sum1) * fold1;

  // g[d] = sum_{s<48} w_s VM[s][d] + w48*([az,1]@LM)[d] + w49*([acz,1]@CM)[d]
  float g0 = 0.f, g1 = 0.f;
  const float* vm = ws + OFF_VM + ln;
  #pragma unroll 8
  for (int s = 0; s < 48; ++s) {
    float vvv = vm[s * 64];
    float s0 = __shfl(w0, s, 64), s1 = __shfl(w1, s, 64);
    g0 = fmaf(s0, vvv, g0); g1 = fmaf(s1, vvv, g1);
  }
  const float* lm = ws + OFF_LM + ln;
  const float* cm = ws + OFF_CM + ln;
  float l0 = lm[64 * 64], l1 = l0;
  float m0 = cm[64 * 64], m1 = m0;
  #pragma unroll 8
  for (int k = 0; k < 64; ++k) {
    float lv = lm[k * 64], cv = cm[k * 64];
    float ak0 = __shfl(a0, k, 64), ak1 = __shfl(a1, k, 64);
    float qk0 = __shfl(c0, k, 64), qk1 = __shfl(c1, k, 64);
    l0 = fmaf(ak0, lv, l0); l1 = fmaf(ak1, lv, l1);
    m0 = fmaf(qk0, cv, m0); m1 = fmaf(qk1, cv, m1);
  }
  float w48_0 = __shfl(w0, 48, 64), w49_0 = __shfl(w0, 49, 64);
  float w48_1 = __shfl(w1, 48, 64), w49_1 = __shfl(w1, 49, 64);
  g0 += w48_0 * l0 + w49_0 * m0;
  g1 += w48_1 * l1 + w49_1 * m1;

  // epilogue: projections off exact covector -> A (sigma-scaled), B (sigma-free)
  #pragma unroll
  for (int s = 0; s < 2; ++s) {
    float g  = (s == 0) ? g0 : g1;
    float cc = (s == 0) ? cc0 : cc1;
    float ee = (s == 0) ? ee0 : ee1;
    int bbs  = bb + s;
    float gc = wred(g * cc);
    float ge = wred(g * ee);
    float ec = wred(ee * cc);
    float en = wred(ee * ee);
    float fc = wred(fbv * cc);
    float fe = wred(fbv * ee);
    if (ln == 0) {
      float A, Bv;
      if (en > 1e-8f) { float r = ec / en; A = gc - ge * r; Bv = fc - fe * r; }
      else { A = gc; Bv = fc; }
      ws[OFF_A  + bbs] = A;
      ws[OFF_Bc + bbs] = Bv;
    }
  }
}

// ===================== K3: apply 1/sigma =====================
__global__ __launch_bounds__(256)
void k3_out(const float* __restrict__ ws, float* __restrict__ out) {
  int b = blockIdx.x * 256 + threadIdx.x;
  float rs = ws[OFF_RS];
  out[b] = ws[OFF_A + b] * rs + ws[OFF_Bc + b];
}

extern "C" void kernel_launch(void* const* d_in, const int* in_sizes, int n_in,
                              void* d_out, int out_size, void* d_ws, size_t ws_size,
                              hipStream_t stream) {
  const float* z     = (const float*)d_in[0];
  const float* rw    = (const float*)d_in[1];
  const float* az    = (const float*)d_in[2];
  const float* arw   = (const float*)d_in[3];
  const float* acz   = (const float*)d_in[4];
  const float* ctrl  = (const float*)d_in[5];
  const float* ecov  = (const float*)d_in[6];
  const float* chemb = (const float*)d_in[7];
  const float* chanc = (const float*)d_in[8];
  const float* aemb  = (const float*)d_in[9];
  const float* aanc  = (const float*)d_in[10];
  const float* zW    = (const float*)d_in[11];
  const float* zb    = (const float*)d_in[12];
  const float* latW  = (const float*)d_in[13];
  const float* latb  = (const float*)d_in[14];
  const float* codeW = (const float*)d_in[15];
  const float* codeb = (const float*)d_in[16];
  const float* Wq    = (const float*)d_in[17];
  const float* Wk    = (const float*)d_in[18];
  const float* Wv    = (const float*)d_in[19];
  const float* Wo    = (const float*)d_in[20];
  const float* fW    = (const float*)d_in[21];
  const float* fb    = (const float*)d_in[22];
  float* ws  = (float*)d_ws;
  float* out = (float*)d_out;

  k1a<<<2004, 256, 0, stream>>>(chemb, aemb, zW, zb, latW, latb, codeW, codeb,
                                Wq, Wk, Wv, Wo, fW, ws);
  k1b<<<375, 256, 0, stream>>>(latb, codeb, aanc, chanc, ws);
  k2_main<<<513, 256, 0, stream>>>(z, rw, az, arw, acz, ctrl, ecov, fb, ws);
  k3_out<<<16, 256, 0, stream>>>(ws, out);
}